// Round 1
// baseline (236.885 us; speedup 1.0000x reference)
//
#include <hip/hip_runtime.h>

// Problem constants
constexpr int kB  = 2;
constexpr int kL  = 8192;   // d*h*w = 8*32*32
constexpr int kC  = 128;    // D_MODEL
constexpr int kE  = 256;    // D_INNER
constexpr int kN  = 16;     // D_STATE
constexpr int kR  = 8;      // DT_RANK
constexpr int kCL = 64;     // scan chunk length
constexpr int kNC = kL / kCL; // 128 chunks per batch

// ---------------------------------------------------------------------------
// Kernel 1: LayerNorm.  x (b,c,L) -> xn (b,L,c)
// ---------------------------------------------------------------------------
__global__ __launch_bounds__(256) void k_ln(const float* __restrict__ x,
                                            const float* __restrict__ ln_w,
                                            const float* __restrict__ ln_b,
                                            float* __restrict__ xn) {
  __shared__ float tile[64][129];
  __shared__ float smu[64], srs[64];
  const int b  = blockIdx.y;
  const int l0 = blockIdx.x * 64;
  const int tid = threadIdx.x;
  const int cc = tid >> 6, lt = tid & 63;
  const float* xb = x + (size_t)b * kC * kL;
  for (int c0 = 0; c0 < kC; c0 += 4) {
    tile[lt][c0 + cc] = xb[(size_t)(c0 + cc) * kL + l0 + lt];
  }
  __syncthreads();
  const int l = tid >> 2, q = tid & 3;
  float s = 0.f, s2 = 0.f;
  #pragma unroll
  for (int i = 0; i < 32; ++i) {
    float v = tile[l][q + 4 * i];
    s += v; s2 += v * v;
  }
  s  += __shfl_xor(s, 1);  s2 += __shfl_xor(s2, 1);
  s  += __shfl_xor(s, 2);  s2 += __shfl_xor(s2, 2);
  const float mu  = s * (1.f / 128.f);
  const float var = s2 * (1.f / 128.f) - mu * mu;
  const float rs  = rsqrtf(var + 1e-5f);
  if (q == 0) { smu[l] = mu; srs[l] = rs; }
  __syncthreads();
  float* xnb = xn + ((size_t)b * kL + l0) * kC;
  for (int idx = tid; idx < 64 * kC; idx += 256) {
    const int li = idx >> 7, c = idx & 127;
    xnb[(size_t)li * kC + c] = (tile[li][c] - smu[li]) * srs[li] * ln_w[c] + ln_b[c];
  }
}

// ---------------------------------------------------------------------------
// Kernel 2: xz = xn @ W_in^T  -> xi (first 256 cols), z (last 256 cols)
// tile: 64 tokens x 128 outputs; grid.y = 4 output slices
// ---------------------------------------------------------------------------
__global__ __launch_bounds__(256) void k_gemm1(const float* __restrict__ xn,
                                               const float* __restrict__ W_in,
                                               float* __restrict__ xi,
                                               float* __restrict__ z) {
  __shared__ float As[64][129];
  __shared__ float Bs[128][129];
  const int b  = blockIdx.z;
  const int l0 = blockIdx.x * 64;
  const int et = blockIdx.y;           // 0..3
  const int tid = threadIdx.x;
  const float* xnb = xn + ((size_t)b * kL + l0) * kC;
  for (int idx = tid; idx < 64 * 128; idx += 256) {
    As[idx >> 7][idx & 127] = xnb[idx];
  }
  const float* Wb = W_in + (size_t)et * 128 * kC;
  for (int idx = tid; idx < 128 * 128; idx += 256) {
    Bs[idx >> 7][idx & 127] = Wb[idx];
  }
  __syncthreads();
  const int tr = tid >> 4, ec = tid & 15;
  const int m0 = tr * 4;
  float acc[4][8];
  #pragma unroll
  for (int i = 0; i < 4; ++i)
    #pragma unroll
    for (int j = 0; j < 8; ++j) acc[i][j] = 0.f;
  #pragma unroll 4
  for (int k = 0; k < 128; ++k) {
    float a[4], w[8];
    #pragma unroll
    for (int i = 0; i < 4; ++i) a[i] = As[m0 + i][k];
    #pragma unroll
    for (int j = 0; j < 8; ++j) w[j] = Bs[ec + 16 * j][k];
    #pragma unroll
    for (int i = 0; i < 4; ++i)
      #pragma unroll
      for (int j = 0; j < 8; ++j) acc[i][j] = fmaf(a[i], w[j], acc[i][j]);
  }
  float* dst = (et < 2) ? xi : z;
  const int ebase = (et & 1) * 128;
  #pragma unroll
  for (int i = 0; i < 4; ++i) {
    const size_t row = ((size_t)b * kL + l0 + m0 + i) * kE;
    #pragma unroll
    for (int j = 0; j < 8; ++j) {
      dst[row + ebase + ec + 16 * j] = acc[i][j];
    }
  }
}

// ---------------------------------------------------------------------------
// Kernel 3: causal depthwise conv (+silu) -> xc ; dbl = xc @ W_x^T ;
//           dt = softplus(dbl[:, :8] @ W_dt^T + b_dt) ; Bm ; Cm
// tile: 32 tokens
// ---------------------------------------------------------------------------
__global__ __launch_bounds__(256) void k_convdbl(const float* __restrict__ xi,
                                                 const float* __restrict__ conv_w,
                                                 const float* __restrict__ conv_b,
                                                 const float* __restrict__ W_x,
                                                 const float* __restrict__ W_dt,
                                                 const float* __restrict__ b_dt,
                                                 float* __restrict__ xc,
                                                 float* __restrict__ dt,
                                                 float* __restrict__ Bm,
                                                 float* __restrict__ Cm) {
  __shared__ float xit[35][256];
  __shared__ float xct[32][260];
  __shared__ float Wxt[40][260];
  __shared__ float dblt[32][40];
  __shared__ float Wdtt[256][8];
  __shared__ float bdtt[256];
  const int b  = blockIdx.y;
  const int l0 = blockIdx.x * 32;
  const int tid = threadIdx.x;
  const float* xib = xi + (size_t)b * kL * kE;
  for (int idx = tid; idx < 35 * 256; idx += 256) {
    const int li = idx >> 8, d = idx & 255;
    const int l = l0 - 3 + li;
    xit[li][d] = (l >= 0) ? xib[(size_t)l * kE + d] : 0.f;
  }
  for (int idx = tid; idx < 40 * 256; idx += 256) {
    Wxt[idx >> 8][idx & 255] = W_x[idx];
  }
  for (int idx = tid; idx < 256 * 8; idx += 256) {
    Wdtt[idx >> 3][idx & 7] = W_dt[idx];
  }
  bdtt[tid] = b_dt[tid];
  __syncthreads();
  // depthwise causal conv + silu
  for (int idx = tid; idx < 32 * 256; idx += 256) {
    const int l = idx >> 8, d = idx & 255;
    const float4 cw = ((const float4*)conv_w)[d];
    float s = conv_b[d] + cw.x * xit[l][d] + cw.y * xit[l + 1][d]
                        + cw.z * xit[l + 2][d] + cw.w * xit[l + 3][d];
    s = s / (1.f + __expf(-s));
    xct[l][d] = s;
    xc[((size_t)b * kL + l0 + l) * kE + d] = s;
  }
  __syncthreads();
  // dbl GEMM: 32 tokens x 40 outputs, K=256
  {
    const int lg = tid >> 3, g = tid & 7;
    float acc[5] = {0.f, 0.f, 0.f, 0.f, 0.f};
    #pragma unroll 4
    for (int k = 0; k < 256; ++k) {
      const float xv = xct[lg][k];
      #pragma unroll
      for (int j = 0; j < 5; ++j) acc[j] = fmaf(xv, Wxt[g * 5 + j][k], acc[j]);
    }
    #pragma unroll
    for (int j = 0; j < 5; ++j) dblt[lg][g * 5 + j] = acc[j];
  }
  __syncthreads();
  // Bm / Cm
  for (int idx = tid; idx < 32 * 16; idx += 256) {
    const int l = idx >> 4, n = idx & 15;
    const size_t o = ((size_t)b * kL + l0 + l) * kN + n;
    Bm[o] = dblt[l][8 + n];
    Cm[o] = dblt[l][24 + n];
  }
  // dt GEMM + softplus
  {
    const int l2 = tid >> 3, dg = tid & 7;
    for (int d = dg; d < 256; d += 8) {
      float s = bdtt[d];
      #pragma unroll
      for (int r = 0; r < 8; ++r) s = fmaf(dblt[l2][r], Wdtt[d][r], s);
      s = fmaxf(s, 0.f) + log1pf(__expf(-fabsf(s)));
      dt[((size_t)b * kL + l0 + l2) * kE + d] = s;
    }
  }
}

// ---------------------------------------------------------------------------
// Kernel 4: scan phase A — per-chunk local scan (zero init) + chunk product
// block: 64 d-channels x 16 n ; thread = (d_sub, n-group of 4)
// ---------------------------------------------------------------------------
__global__ __launch_bounds__(256) void k_scanA(const float* __restrict__ dt,
                                               const float* __restrict__ xc,
                                               const float* __restrict__ Bm,
                                               const float* __restrict__ A_log,
                                               float* __restrict__ hloc,
                                               float* __restrict__ aprod) {
  __shared__ float dtt[kCL][64];
  __shared__ float xctl[kCL][64];
  __shared__ float Bmt[kCL][16];
  const int b  = blockIdx.z;
  const int ch = blockIdx.x;
  const int d0 = blockIdx.y * 64;
  const int l0 = ch * kCL;
  const int tid = threadIdx.x;
  const size_t tb = (size_t)b * kL + l0;
  for (int idx = tid; idx < kCL * 64; idx += 256) {
    const int li = idx >> 6, d = idx & 63;
    dtt[li][d]  = dt[(tb + li) * kE + d0 + d];
    xctl[li][d] = xc[(tb + li) * kE + d0 + d];
  }
  for (int idx = tid; idx < kCL * 16; idx += 256) {
    const int li = idx >> 4, n = idx & 15;
    Bmt[li][n] = Bm[(tb + li) * kN + n];
  }
  __syncthreads();
  const int ds = tid >> 2, ng = tid & 3;
  const int d = d0 + ds;
  float Av[4];
  #pragma unroll
  for (int j = 0; j < 4; ++j) Av[j] = -__expf(A_log[d * kN + ng * 4 + j]);
  float h[4] = {0.f, 0.f, 0.f, 0.f};
  float sdt = 0.f;
  for (int l = 0; l < kCL; ++l) {
    const float dtv = dtt[l][ds];
    const float dx  = dtv * xctl[l][ds];
    sdt += dtv;
    #pragma unroll
    for (int j = 0; j < 4; ++j) {
      const float dA = __expf(Av[j] * dtv);
      h[j] = fmaf(dA, h[j], Bmt[l][ng * 4 + j] * dx);
    }
  }
  const size_t base = (((size_t)b * kNC + ch) * kE + d) * kN + ng * 4;
  *(float4*)&hloc[base] = make_float4(h[0], h[1], h[2], h[3]);
  float4 ap;
  ap.x = __expf(Av[0] * sdt); ap.y = __expf(Av[1] * sdt);
  ap.z = __expf(Av[2] * sdt); ap.w = __expf(Av[3] * sdt);
  *(float4*)&aprod[base] = ap;
}

// ---------------------------------------------------------------------------
// Kernel 5: sequential prefix over chunks (tiny)
// ---------------------------------------------------------------------------
__global__ __launch_bounds__(256) void k_prefix(const float* __restrict__ hloc,
                                                const float* __restrict__ aprod,
                                                float* __restrict__ hinit) {
  const int t = blockIdx.x * 256 + threadIdx.x;  // 8192 = B*E*N
  const int b = t >> 12, dn = t & 4095;
  float h = 0.f;
  for (int c = 0; c < kNC; ++c) {
    const size_t idx = ((size_t)b * kNC + c) * 4096 + dn;
    hinit[idx] = h;
    h = fmaf(aprod[idx], h, hloc[idx]);
  }
}

// ---------------------------------------------------------------------------
// Kernel 6: scan phase C — real scan with correct init, y = sum_n h*C,
//           fused gating: y = (y + xc*D) * silu(z)
// ---------------------------------------------------------------------------
__global__ __launch_bounds__(256) void k_scanC(const float* __restrict__ dt,
                                               const float* __restrict__ xc,
                                               const float* __restrict__ Bm,
                                               const float* __restrict__ Cm,
                                               const float* __restrict__ z,
                                               const float* __restrict__ A_log,
                                               const float* __restrict__ Dp,
                                               const float* __restrict__ hinit,
                                               float* __restrict__ y) {
  __shared__ float dtt[kCL][64];
  __shared__ float xctl[kCL][64];
  __shared__ float Bmt[kCL][16];
  __shared__ float Cmt[kCL][16];
  __shared__ float yt[kCL][64];
  const int b  = blockIdx.z;
  const int ch = blockIdx.x;
  const int d0 = blockIdx.y * 64;
  const int l0 = ch * kCL;
  const int tid = threadIdx.x;
  const size_t tb = (size_t)b * kL + l0;
  for (int idx = tid; idx < kCL * 64; idx += 256) {
    const int li = idx >> 6, d = idx & 63;
    dtt[li][d]  = dt[(tb + li) * kE + d0 + d];
    xctl[li][d] = xc[(tb + li) * kE + d0 + d];
  }
  for (int idx = tid; idx < kCL * 16; idx += 256) {
    const int li = idx >> 4, n = idx & 15;
    Bmt[li][n] = Bm[(tb + li) * kN + n];
    Cmt[li][n] = Cm[(tb + li) * kN + n];
  }
  __syncthreads();
  const int ds = tid >> 2, ng = tid & 3;
  const int d = d0 + ds;
  float Av[4];
  #pragma unroll
  for (int j = 0; j < 4; ++j) Av[j] = -__expf(A_log[d * kN + ng * 4 + j]);
  const float4 hv = *(const float4*)&hinit[(((size_t)b * kNC + ch) * kE + d) * kN + ng * 4];
  float h[4] = {hv.x, hv.y, hv.z, hv.w};
  for (int l = 0; l < kCL; ++l) {
    const float dtv = dtt[l][ds];
    const float dx  = dtv * xctl[l][ds];
    float yp = 0.f;
    #pragma unroll
    for (int j = 0; j < 4; ++j) {
      const float dA = __expf(Av[j] * dtv);
      h[j] = fmaf(dA, h[j], Bmt[l][ng * 4 + j] * dx);
      yp = fmaf(h[j], Cmt[l][ng * 4 + j], yp);
    }
    yp += __shfl_xor(yp, 1);
    yp += __shfl_xor(yp, 2);
    if (ng == 0) yt[l][ds] = yp;
  }
  __syncthreads();
  for (int idx = tid; idx < kCL * 64; idx += 256) {
    const int li = idx >> 6, dd = idx & 63;
    float yv = fmaf(xctl[li][dd], Dp[d0 + dd], yt[li][dd]);
    const float zv = z[(tb + li) * kE + d0 + dd];
    yv *= zv / (1.f + __expf(-zv));
    y[(tb + li) * kE + d0 + dd] = yv;
  }
}

// ---------------------------------------------------------------------------
// Kernel 7: out = y @ W_out^T, written transposed to (b, c, L)
// ---------------------------------------------------------------------------
__global__ __launch_bounds__(256) void k_gemm3(const float* __restrict__ y,
                                               const float* __restrict__ W_out,
                                               float* __restrict__ out) {
  __shared__ float As[64][129];
  __shared__ float Bs[128][129];
  const int b  = blockIdx.y;
  const int l0 = blockIdx.x * 64;
  const int tid = threadIdx.x;
  const int tr = tid >> 4, ec = tid & 15;
  const int m0 = tr * 4;
  float acc[4][8];
  #pragma unroll
  for (int i = 0; i < 4; ++i)
    #pragma unroll
    for (int j = 0; j < 8; ++j) acc[i][j] = 0.f;
  for (int k0 = 0; k0 < kE; k0 += 128) {
    __syncthreads();
    for (int idx = tid; idx < 64 * 128; idx += 256) {
      const int m = idx >> 7, k = idx & 127;
      As[m][k] = y[((size_t)b * kL + l0 + m) * kE + k0 + k];
    }
    for (int idx = tid; idx < 128 * 128; idx += 256) {
      const int n = idx >> 7, k = idx & 127;
      Bs[n][k] = W_out[(size_t)n * kE + k0 + k];
    }
    __syncthreads();
    #pragma unroll 4
    for (int k = 0; k < 128; ++k) {
      float a[4], w[8];
      #pragma unroll
      for (int i = 0; i < 4; ++i) a[i] = As[m0 + i][k];
      #pragma unroll
      for (int j = 0; j < 8; ++j) w[j] = Bs[ec + 16 * j][k];
      #pragma unroll
      for (int i = 0; i < 4; ++i)
        #pragma unroll
        for (int j = 0; j < 8; ++j) acc[i][j] = fmaf(a[i], w[j], acc[i][j]);
    }
  }
  __syncthreads();
  float* ot = &Bs[0][0];  // reuse as [64][129] out tile (m-major)
  #pragma unroll
  for (int i = 0; i < 4; ++i)
    #pragma unroll
    for (int j = 0; j < 8; ++j)
      ot[(size_t)(m0 + i) * 129 + ec + 16 * j] = acc[i][j];
  __syncthreads();
  for (int idx = tid; idx < 64 * 128; idx += 256) {
    const int c = idx >> 6, lt = idx & 63;
    out[((size_t)b * kC + c) * kL + l0 + lt] = ot[(size_t)lt * 129 + c];
  }
}

// ---------------------------------------------------------------------------
extern "C" void kernel_launch(void* const* d_in, const int* in_sizes, int n_in,
                              void* d_out, int out_size, void* d_ws, size_t ws_size,
                              hipStream_t stream) {
  (void)in_sizes; (void)n_in; (void)out_size; (void)ws_size;
  const float* x      = (const float*)d_in[0];
  const float* ln_w   = (const float*)d_in[1];
  const float* ln_b   = (const float*)d_in[2];
  const float* W_in   = (const float*)d_in[3];
  const float* conv_w = (const float*)d_in[4];
  const float* conv_b = (const float*)d_in[5];
  const float* W_x    = (const float*)d_in[6];
  const float* W_dt   = (const float*)d_in[7];
  const float* b_dt   = (const float*)d_in[8];
  const float* A_log  = (const float*)d_in[9];
  const float* Dp     = (const float*)d_in[10];
  const float* W_out  = (const float*)d_in[11];
  float* out = (float*)d_out;
  float* ws  = (float*)d_ws;

  // workspace layout (floats); total 20,447,232 floats = ~81.8 MB
  float* xn    = ws;                  // 2,097,152  (reused below by hloc/aprod)
  float* xi    = ws + 2097152;        // 4,194,304  (reused below by y)
  float* z     = ws + 6291456;        // 4,194,304
  float* xc    = ws + 10485760;       // 4,194,304
  float* dt    = ws + 14680064;       // 4,194,304
  float* Bm    = ws + 18874368;       //   262,144
  float* Cm    = ws + 19136512;       //   262,144
  float* hinit = ws + 19398656;       // 1,048,576
  float* hloc  = xn;                  // 1,048,576 (xn dead after gemm1)
  float* aprod = xn + 1048576;        // 1,048,576
  float* y     = xi;                  // xi dead after conv

  k_ln     <<<dim3(kL / 64, kB),        256, 0, stream>>>(x, ln_w, ln_b, xn);
  k_gemm1  <<<dim3(kL / 64, 4, kB),     256, 0, stream>>>(xn, W_in, xi, z);
  k_convdbl<<<dim3(kL / 32, kB),        256, 0, stream>>>(xi, conv_w, conv_b, W_x, W_dt, b_dt, xc, dt, Bm, Cm);
  k_scanA  <<<dim3(kNC, kE / 64, kB),   256, 0, stream>>>(dt, xc, Bm, A_log, hloc, aprod);
  k_prefix <<<dim3(kB * kE * kN / 256), 256, 0, stream>>>(hloc, aprod, hinit);
  k_scanC  <<<dim3(kNC, kE / 64, kB),   256, 0, stream>>>(dt, xc, Bm, Cm, z, A_log, Dp, hinit, y);
  k_gemm3  <<<dim3(kL / 64, kB),        256, 0, stream>>>(y, W_out, out);
}